// Round 4
// baseline (107.534 us; speedup 1.0000x reference)
//
#include <hip/hip_runtime.h>

typedef short short8 __attribute__((ext_vector_type(8)));
typedef float f32x4 __attribute__((ext_vector_type(4)));

// K = 256 (ones-column folded into per-rule bias in the epilogue)

// workspace layout (bytes)
#define OFF_CP   0ULL        // cp bf16 [1024][256]   524288
#define OFF_CB   524288ULL   // bias f32 [1024]         4096
#define OFF_A2   528384ULL   // a2 f32  [1024][4]      16384
#define OFF_C2   544768ULL   // c2 f32  [1024][4]      16384
#define OFF_IX   561152ULL   // packed fidx u32 [1024]  4096
#define OFF_PAIR 565248ULL   // packed pairs u16 [128]   256
#define OFF_NUM  565504ULL   // num f32 [16384]        65536
#define OFF_DEN  631040ULL   // den f32 [16384]        65536

#define XS 65  // xa LDS stride: bank = (row + f) % 32 -> gathers ~2-way (free)

__device__ __forceinline__ unsigned short f2bf(float f) {
  unsigned u = __float_as_uint(f);
  return (unsigned short)((u + 0x7FFFu + ((u >> 16) & 1u)) >> 16);
}

// ---------------- prep: cp->bf16 + bias, rule consts, pair pack, zero num/den
__global__ __launch_bounds__(256) void prep_kernel(
    const float* __restrict__ pp, const float* __restrict__ th,
    const float* __restrict__ sg, const float* __restrict__ mk,
    const float* __restrict__ cp, const int* __restrict__ fidx,
    const int* __restrict__ pairs, unsigned char* __restrict__ ws)
{
  unsigned short* cp_out = (unsigned short*)(ws + OFF_CP);
  float* cbo = (float*)(ws + OFF_CB);
  float* a2o = (float*)(ws + OFF_A2);
  float* c2o = (float*)(ws + OFF_C2);
  unsigned* ixo = (unsigned*)(ws + OFF_IX);
  unsigned short* pro = (unsigned short*)(ws + OFF_PAIR);
  int bid = blockIdx.x, t = threadIdx.x;

  if (bid < 256) {  // cp cols 0..255 -> bf16 [1024][256]
    int e = bid * 1024 + t * 4;
    int r = e >> 8, c = e & 255;
    const float* src = cp + (size_t)r * 257 + c;
#pragma unroll
    for (int q = 0; q < 4; ++q) cp_out[e + q] = f2bf(src[q]);
  } else if (bid < 260) {  // rule consts + bias
    int r = (bid - 256) * 256 + t;
    float p = pp[r];
    unsigned pk = 0;
#pragma unroll
    for (int l = 0; l < 4; ++l) {
      float m = mk[r * 4 + l], s = sg[r * 4 + l], tt = th[r * 4 + l];
      float A, C;
      if (m != 0.f) { A = -1.44269504f * p * s; C = 1.44269504f * p * s * tt; }
      else          { A = 0.f;                  C = -126.f; }  // exp2(-126) ~ 0 -> factor 1
      a2o[r * 4 + l] = A; c2o[r * 4 + l] = C;
      pk |= ((unsigned)fidx[r * 4 + l] & 0xFFu) << (8 * l);
    }
    ixo[r] = pk;
    cbo[r] = cp[(size_t)r * 257 + 256];  // ones-column coefficient
  } else if (bid == 260) {  // pack interaction pairs
    if (t < 128)
      pro[t] = (unsigned short)((pairs[2 * t] & 0xFF) | ((pairs[2 * t + 1] & 0xFF) << 8));
  } else {  // zero num/den (ws is re-poisoned 0xAA before every call)
    float* dst = (float*)(ws + (bid == 261 ? OFF_NUM : OFF_DEN));
#pragma unroll
    for (int q = 0; q < 64; ++q) dst[q * 256 + t] = 0.f;
  }
}

// ---------------- main: C[rule][batch] = cp . p^T (K=256), fused firing ----
// grid (256 b-blocks x 4 r-blocks); block = 256 rules x 64 batches; 3 blocks/CU.
__global__ __launch_bounds__(256, 3) void main_kernel(
    const unsigned char* __restrict__ ws,
    const float* __restrict__ x, const float* __restrict__ att,
    float* __restrict__ numg, float* __restrict__ deng)
{
  __shared__ float xa[64 * XS];           // 16640 B
  __shared__ short lCP[256 * 32];         // 16384 B, 16B-block XOR swizzle
  __shared__ short lP[64 * 32];           //  4096 B, same swizzle
  __shared__ unsigned short lPair[128];   //   256 B

  const unsigned short* CP = (const unsigned short*)(ws + OFF_CP);
  const float* CB = (const float*)(ws + OFF_CB);
  const float4* A2p = (const float4*)(ws + OFF_A2);
  const float4* C2p = (const float4*)(ws + OFF_C2);
  const unsigned* IX = (const unsigned*)(ws + OFF_IX);
  const unsigned short* PRW = (const unsigned short*)(ws + OFF_PAIR);

  int t = threadIdx.x, l = t & 63, w = t >> 6;
  int g = l >> 4, lr = l & 15;
  int b0 = blockIdx.x * 64, r0 = blockIdx.y * 256;

  if (t < 128) lPair[t] = PRW[t];
  {  // stage x_att tile (64 rows x 64 f32); scalar stores (stride-65, 2-way banks)
#pragma unroll
    for (int i = 0; i < 4; ++i) {
      int idx = t + i * 256, row = idx >> 4, c4 = idx & 15;
      float4 a4 = ((const float4*)att)[c4];
      float4 v = ((const float4*)(x + (size_t)(b0 + row) * 64))[c4];
      float* dst = &xa[row * XS + c4 * 4];
      dst[0] = v.x * a4.x; dst[1] = v.y * a4.y;
      dst[2] = v.z * a4.z; dst[3] = v.w * a4.w;
    }
  }
  __syncthreads();  // xa + lPair ready

  f32x4 acc[4][4];
#pragma unroll
  for (int mi = 0; mi < 4; ++mi)
#pragma unroll
    for (int ni = 0; ni < 4; ++ni)
      acc[mi][ni] = (f32x4){0.f, 0.f, 0.f, 0.f};

  int row2 = t >> 2, q = t & 3;                 // staging ids: 64 rows x 4 col-blocks
  int sw2 = (row2 ^ (row2 >> 2)) & 3;
  const float* xr2 = &xa[row2 * XS];
  const unsigned short* cpbase = CP + (size_t)(r0 + row2) * 256 + q * 8;

  // 2-deep cpr prefetch: loads for ks+2 issued in the store phase -> ~2 loop
  // bodies (>=500 cyc) of latency cover; loads stay in flight across barriers.
  short8 cpr[2][4];
#pragma unroll
  for (int i = 0; i < 4; ++i) {
    cpr[0][i] = *(const short8*)(cpbase + (size_t)i * 64 * 256);
    cpr[1][i] = *(const short8*)(cpbase + (size_t)i * 64 * 256 + 32);
  }

#pragma unroll 2  // static cpr[ks&1] indexing (avoid scratch), kills rotation movs
  for (int ks = 0; ks < 8; ++ks) {
    int k0 = ks * 32;
    int fb = k0 + q * 8;
    // -- generate p feature block fb..fb+7 for batch row row2 (wave-uniform ks branch)
    short8 vp;
    if (ks < 2) {                 // raw x_att
#pragma unroll
      for (int j = 0; j < 8; ++j) vp[j] = f2bf(xr2[fb + j]);
    } else if (ks < 4) {          // squares
#pragma unroll
      for (int j = 0; j < 8; ++j) { float u = xr2[fb - 64 + j]; vp[j] = f2bf(u * u); }
    } else {                      // interaction pairs (ks 4..7)
      const unsigned* pw = (const unsigned*)&lPair[fb - 128];
#pragma unroll
      for (int u = 0; u < 4; ++u) {
        unsigned pk = pw[u];
        vp[2 * u]     = f2bf(xr2[pk & 255] * xr2[(pk >> 8) & 255]);
        vp[2 * u + 1] = f2bf(xr2[(pk >> 16) & 255] * xr2[pk >> 24]);
      }
    }
    __syncthreads();  // prior iter's frag reads complete
#pragma unroll
    for (int i = 0; i < 4; ++i) {
      int rowc = row2 + i * 64;
      int swc = (rowc ^ (rowc >> 2)) & 3;
      *(short8*)&lCP[rowc * 32 + ((q ^ swc) * 8)] = cpr[ks & 1][i];
    }
    *(short8*)&lP[row2 * 32 + ((q ^ sw2) * 8)] = vp;
    if (ks < 6) {  // refill slot (ks&1) with tile ks+2
#pragma unroll
      for (int i = 0; i < 4; ++i)
        cpr[ks & 1][i] = *(const short8*)(cpbase + (size_t)i * 64 * 256 + k0 + 64);
    }
    __syncthreads();
    // -- fragments (XOR-swizzled reads, 2-way max): bF once, aF per-mi
    short8 bF[4];
#pragma unroll
    for (int ni = 0; ni < 4; ++ni) {
      int row = ni * 16 + lr;
      int s = (row ^ (row >> 2)) & 3;
      bF[ni] = *(const short8*)&lP[row * 32 + ((g ^ s) * 8)];
    }
#pragma unroll
    for (int mi = 0; mi < 4; ++mi) {
      int row = w * 64 + mi * 16 + lr;
      int s = (row ^ (row >> 2)) & 3;
      short8 aF = *(const short8*)&lCP[row * 32 + ((g ^ s) * 8)];
#pragma unroll
      for (int ni = 0; ni < 4; ++ni)
        acc[mi][ni] = __builtin_amdgcn_mfma_f32_16x16x32_bf16(aF, bF[ni], acc[mi][ni], 0, 0, 0);
    }
  }

  // ---- fused firing epilogue. C layout: row = rule = w*64+mi*16+g*4+j (g-uniform
  // per 16 lanes), col = batch = ni*16+lr. Gather bank = (16ni+lr+f)%32: ~2-way.
  float num[4] = {0.f, 0.f, 0.f, 0.f}, den[4] = {0.f, 0.f, 0.f, 0.f};
#pragma unroll
  for (int mi = 0; mi < 4; ++mi) {
#pragma unroll
    for (int j = 0; j < 4; ++j) {
      int rule = r0 + w * 64 + mi * 16 + (g << 2) + j;
      float4 A2 = A2p[rule], C2 = C2p[rule];
      unsigned pk = IX[rule];
      float bias = CB[rule];
      int f0 = pk & 255, f1 = (pk >> 8) & 255, f2 = (pk >> 16) & 255, f3 = pk >> 24;
#pragma unroll
      for (int ni = 0; ni < 4; ++ni) {
        const float* xr = &xa[(ni * 16 + lr) * XS];
        float D = 1.f;
        float e0 = exp2f(fmaf(A2.x, xr[f0], C2.x)); D = fmaf(D, e0, D);
        float e1 = exp2f(fmaf(A2.y, xr[f1], C2.y)); D = fmaf(D, e1, D);
        float e2 = exp2f(fmaf(A2.z, xr[f2], C2.z)); D = fmaf(D, e2, D);
        float e3 = exp2f(fmaf(A2.w, xr[f3], C2.w)); D = fmaf(D, e3, D);
        float fir = __builtin_amdgcn_rcpf(D);
        num[ni] = fmaf(fir, acc[mi][ni][j] + bias, num[ni]);
        den[ni] += fir;
      }
    }
  }

  // reduce over the 4 lane-groups (g) which hold different rules of same batch col
#pragma unroll
  for (int ni = 0; ni < 4; ++ni) {
    float n = num[ni], d = den[ni];
    n += __shfl_xor(n, 16, 64); n += __shfl_xor(n, 32, 64);
    d += __shfl_xor(d, 16, 64); d += __shfl_xor(d, 32, 64);
    num[ni] = n; den[ni] = d;
  }
  float nv = 0.f, dv = 0.f;
#pragma unroll
  for (int ni = 0; ni < 4; ++ni)
    if (g == ni) { nv = num[ni]; dv = den[ni]; }
  atomicAdd(&numg[b0 + (g << 4) + lr], nv);
  atomicAdd(&deng[b0 + (g << 4) + lr], dv);
}

// ---------------- finalize ----------------
__global__ __launch_bounds__(256) void fin_kernel(
    const float* __restrict__ numg, const float* __restrict__ deng,
    float* __restrict__ y)
{
  int i = blockIdx.x * 256 + threadIdx.x;
  y[i] = numg[i] / (deng[i] + 1e-8f);
}

extern "C" void kernel_launch(void* const* d_in, const int* in_sizes, int n_in,
                              void* d_out, int out_size, void* d_ws, size_t ws_size,
                              hipStream_t stream) {
  (void)in_sizes; (void)n_in; (void)out_size; (void)ws_size;
  const float* x    = (const float*)d_in[0];
  const float* att  = (const float*)d_in[1];
  const float* pp   = (const float*)d_in[2];
  const float* th   = (const float*)d_in[3];
  const float* sg   = (const float*)d_in[4];
  const float* mk   = (const float*)d_in[5];
  const float* cp   = (const float*)d_in[6];
  const int* fidx   = (const int*)d_in[7];
  const int* pairs  = (const int*)d_in[8];
  unsigned char* ws = (unsigned char*)d_ws;
  float* numg = (float*)(ws + OFF_NUM);
  float* deng = (float*)(ws + OFF_DEN);

  prep_kernel<<<263, 256, 0, stream>>>(pp, th, sg, mk, cp, fidx, pairs, ws);
  main_kernel<<<dim3(256, 4), 256, 0, stream>>>(ws, x, att, numg, deng);
  fin_kernel<<<64, 256, 0, stream>>>(numg, deng, (float*)d_out);
}